// Round 6
// baseline (538.839 us; speedup 1.0000x reference)
//
#include <hip/hip_runtime.h>

typedef unsigned short bf16_t;
typedef short s16x8 __attribute__((ext_vector_type(8)));
typedef float f32x4 __attribute__((ext_vector_type(4)));

// ===========================================================================
// Round 13 (R12 passed @527us). R12 post-mortem: reg-pipeline was NULL
// (103.6us; VGPR=76 proves compiler folded the pipeline arrays and re-sunk
// loads -- hipcc defeats source pipelining, as guide warns). Fact: THREE
// max-different gemm1 schedules (no-LDS / LDS-staged / reg-pipelined) all
// ~103us, exact logical bytes, MfmaUtil 7%, VALU 15%. Remaining shared
// suspects: (a) epilogue with dependent scattered dinv load inside the
// 32-iter store loop + shfl/pack chains (VALU 15% ~= 15us); (b) divergent
// 16-line VMEM issue throttle. (a) is cheaply testable this round.
// Changes:
//  - gemm1p/gemm2p: hoist dinv[8]/bias[4] into regs BEFORE the K-loop
//    (overlaps main loads); epilogue = pure pack+store. Discriminating:
//    75-85us => epilogue chain confirmed; ~103 => accept shape ceiling.
//  - k_gather: 4 nodes/wave x uint4 (16 lanes/node, 16B/lane): 32 rows in
//    flight/wave (2x MLP), half the load instrs; grid N/16=6250.
// ===========================================================================

#define NBKT 782   // ceil(100000/128) buckets of 128 nodes
#define BSH  7
#define BMSK 127
#define CAPS 512   // per (bucket,sub) capacity: mean 256 + 16 sigma

__device__ __forceinline__ float bf2f(unsigned short u) {
    unsigned int v = ((unsigned int)u) << 16;
    float f;
    __builtin_memcpy(&f, &v, 4);
    return f;
}
__device__ __forceinline__ unsigned short f2bf(float f) {
    unsigned int x;
    __builtin_memcpy(&x, &f, 4);
    unsigned int r = x + 0x7fffu + ((x >> 16) & 1u);
    return (unsigned short)(r >> 16);
}
__device__ __forceinline__ unsigned pack2(float a, float b) {
    return (unsigned)f2bf(a) | ((unsigned)f2bf(b) << 16);
}
__device__ __forceinline__ float ldf(const void* p, long long i, unsigned f32) {
    return f32 ? ((const float*)p)[i] : bf2f(((const unsigned short*)p)[i]);
}
__device__ __forceinline__ int ldi(const void* p, long long i, unsigned i64) {
    return i64 ? (int)((const long long*)p)[i] : ((const int*)p)[i];
}
__device__ __forceinline__ s16x8 ld8u(const unsigned short* p) {
    return *(const s16x8*)p;   // 16B aligned at all call sites
}
__device__ __forceinline__ f32x4 mfma16(s16x8 a, s16x8 b, f32x4 c) {
    return __builtin_amdgcn_mfma_f32_16x16x32_bf16(a, b, c, 0, 0, 0);
}
// fp32 -> (hi, lo) bf16 fragments, 8 consecutive floats
__device__ __forceinline__ void cvt_hl(const float* p, s16x8& hi, s16x8& lo) {
    const float4 u = *(const float4*)p;
    const float4 w = *(const float4*)(p + 4);
    float v[8] = {u.x, u.y, u.z, u.w, w.x, w.y, w.z, w.w};
#pragma unroll
    for (int j = 0; j < 8; ++j) {
        unsigned short h = f2bf(v[j]);
        hi[j] = (short)h;
        lo[j] = (short)f2bf(v[j] - bf2f(h));
    }
}

// ---- detector + btail zero: flags[0]=x_f32, flags[1]=W_f32, flags[2]=ei_i64
__global__ __launch_bounds__(256) void k_detect(const void* x, const void* W1,
                                                const void* ei, unsigned* flags,
                                                int* __restrict__ btail) {
    __shared__ float smx[256];
    __shared__ float smw[256];
    __shared__ int   szc[256];
    int tid = threadIdx.x;
    for (int i = tid; i < NBKT * 8; i += 256) btail[i] = 0;
    const unsigned short* xu = (const unsigned short*)x;
    float mx = 0.f;
    for (int i = tid; i < 4096; i += 256) {
        unsigned short w = xu[i];
        if ((w & 0x7fffu) >= 0x7f80u) mx = 1e30f;
        else { float f = fabsf(bf2f(w)); if (f > mx) mx = f; }
    }
    smx[tid] = mx;
    const unsigned short* wu = (const unsigned short*)W1;
    float mw = 0.f;
    for (int i = tid; i < 4096; i += 256) {
        unsigned short w = wu[i];
        if ((w & 0x7fffu) >= 0x7f80u) mw = 1e30f;
        else { float f = fabsf(bf2f(w)); if (f > mw) mw = f; }
    }
    smw[tid] = mw;
    const int* eu = (const int*)ei;
    int zc = 0;
    for (int i = tid; i < 128; i += 256)
        if ((i & 1) && eu[i] == 0) ++zc;
    szc[tid] = zc;
    __syncthreads();
    for (int off = 128; off > 0; off >>= 1) {
        if (tid < off) {
            if (smx[tid + off] > smx[tid]) smx[tid] = smx[tid + off];
            if (smw[tid + off] > smw[tid]) smw[tid] = smw[tid + off];
            szc[tid] += szc[tid + off];
        }
        __syncthreads();
    }
    if (tid == 0) {
        flags[0] = (smx[0] > 1e4f) ? 1u : 0u;
        flags[1] = (smw[0] > 10.f) ? 1u : 0u;
        flags[2] = (szc[0] >= 56) ? 1u : 0u;
    }
}

// ---- phase A: bucket scatter (append streams, XCD-local counters) ----------
__global__ __launch_bounds__(256) void k_bucket(const void* ei, const unsigned* det,
                                                int* __restrict__ btail,
                                                unsigned* __restrict__ bstore,
                                                int E, int N) {
    int e = blockIdx.x * 256 + threadIdx.x;
    if (e >= E) return;
    unsigned i64 = det[2];
    int s = ldi(ei, e, i64);
    int d = ldi(ei, (long long)E + e, i64);
    if ((unsigned)d >= (unsigned)N) return;
    int b = d >> BSH;
    int sub = blockIdx.x & 7;
    int slot = atomicAdd(&btail[sub * NBKT + b], 1);
    if (slot < CAPS) {
        unsigned src = ((unsigned)s < (unsigned)N) ? (unsigned)s : (unsigned)d;
        bstore[((long long)(b * 8 + sub)) * CAPS + slot] =
            ((unsigned)(d & BMSK) << 24) | src;
    }
}

// ---- phase B1: per-bucket histogram -> cnt + dinv (coalesced) --------------
__global__ __launch_bounds__(256) void k_bhist(const int* __restrict__ btail,
                                               const unsigned* __restrict__ bstore,
                                               int* __restrict__ cnt,
                                               float* __restrict__ dinv, int N) {
    __shared__ int lh[128];
    __shared__ int ln[8];
    const int b = blockIdx.x;
    const int tid = threadIdx.x;
    if (tid < 128) lh[tid] = 0;
    if (tid < 8) {
        int t = btail[tid * NBKT + b];
        ln[tid] = t < CAPS ? t : CAPS;
    }
    __syncthreads();
#pragma unroll 1
    for (int s = 0; s < 8; ++s) {
        int n = ln[s];
        const unsigned* base = &bstore[((long long)(b * 8 + s)) * CAPS];
        for (int i = tid; i < n; i += 256)
            atomicAdd(&lh[base[i] >> 24], 1);
    }
    __syncthreads();
    int node = b * 128 + tid;
    if (tid < 128 && node < N) {
        cnt[node] = lh[tid];
        dinv[node] = rsqrtf((float)lh[tid] + 1.0f);  // +1 self-loop
    }
}

// ---- exclusive scan (2 dispatches) -----------------------------------------
__global__ __launch_bounds__(256) void k_scan_blk(const int* __restrict__ cnt,
                                                  int* __restrict__ pos,
                                                  int* __restrict__ bsum, int N) {
    __shared__ int sh[256];
    const int tid = threadIdx.x;
    const int base = blockIdx.x * 1024 + tid * 4;
    int v[4];
#pragma unroll
    for (int j = 0; j < 4; ++j) v[j] = (base + j < N) ? cnt[base + j] : 0;
    int s = v[0] + v[1] + v[2] + v[3];
    sh[tid] = s;
    __syncthreads();
    for (int off = 1; off < 256; off <<= 1) {
        int t = (tid >= off) ? sh[tid - off] : 0;
        __syncthreads();
        sh[tid] += t;
        __syncthreads();
    }
    int run = sh[tid] - s;
#pragma unroll
    for (int j = 0; j < 4; ++j) {
        if (base + j < N) pos[base + j] = run;
        run += v[j];
    }
    if (tid == 255) bsum[blockIdx.x] = sh[255];
}

// scan_top folded in: each block sums bsum[0..blockIdx) itself (<=97 reads).
__global__ __launch_bounds__(256) void k_scan_add(int* __restrict__ pos,
                                                  const int* __restrict__ bsum, int N) {
    __shared__ int sadd;
    if (threadIdx.x == 0) {
        int a = 0;
        for (int i = 0; i < blockIdx.x; ++i) a += bsum[i];
        sadd = a;
    }
    __syncthreads();
    int add = sadd;
    int base = blockIdx.x * 1024;
    for (int i = threadIdx.x; i < 1024; i += 256)
        if (base + i < N) pos[base + i] += add;
}

// ---- phase B2: per-bucket placement + coalesced srt write ------------------
__global__ __launch_bounds__(256) void k_emit(const int* __restrict__ btail,
                                              const unsigned* __restrict__ bstore,
                                              const int* __restrict__ pos,
                                              int* __restrict__ srt, int N) {
    __shared__ int lstart[128];
    __shared__ int loff[128];
    __shared__ int ln[8];
    __shared__ int stage[4096];   // <= 8*CAPS
    const int b = blockIdx.x;
    const int tid = threadIdx.x;
    const int base0 = pos[b * 128];          // b*128 <= 99968 < N always
    if (tid < 128) {
        int node = b * 128 + tid;
        lstart[tid] = (node < N) ? (pos[node] - base0) : 0;
        loff[tid] = 0;
    }
    if (tid < 8) {
        int t = btail[tid * NBKT + b];
        ln[tid] = t < CAPS ? t : CAPS;
    }
    __syncthreads();
#pragma unroll 1
    for (int s = 0; s < 8; ++s) {
        int n = ln[s];
        const unsigned* bp = &bstore[((long long)(b * 8 + s)) * CAPS];
        for (int i = tid; i < n; i += 256) {
            unsigned rec = bp[i];
            int dl = rec >> 24;
            int slot = atomicAdd(&loff[dl], 1);
            stage[lstart[dl] + slot] = (int)(rec & 0xffffffu);
        }
    }
    __syncthreads();
    int total = ln[0] + ln[1] + ln[2] + ln[3] + ln[4] + ln[5] + ln[6] + ln[7];
    for (int i = tid; i < total; i += 256)
        srt[base0 + i] = stage[i];
}

// ---- weight transpose + hi/lo bf16 split (both layers, one dispatch) -------
__global__ __launch_bounds__(256) void k_wsplit(const void* W1, const void* Wmu,
                                                const void* Wlv, const unsigned* det,
                                                unsigned short* __restrict__ bt1h,
                                                unsigned short* __restrict__ bt1l,
                                                unsigned short* __restrict__ bt2h,
                                                unsigned short* __restrict__ bt2l) {
    int idx = blockIdx.x * 256 + threadIdx.x;
    unsigned wf = det[1];
    if (idx < 256 * 128) {
        int k = idx >> 7, n = idx & 127;
        float w = ldf(W1, idx, wf);
        unsigned short h = f2bf(w);
        bt1h[(long long)n * 256 + k] = h;
        bt1l[(long long)n * 256 + k] = f2bf(w - bf2f(h));
    } else if (idx < 256 * 128 + 128 * 128) {
        int j = idx - 256 * 128;
        int k = j >> 7, n = j & 127;
        float w = (n < 64) ? ldf(Wmu, (long long)k * 64 + n, wf)
                           : ldf(Wlv, (long long)k * 64 + (n - 64), wf);
        unsigned short h = f2bf(w);
        bt2h[(long long)n * 128 + k] = h;
        bt2l[(long long)n * 128 + k] = f2bf(w - bf2f(h));
    }
}

// ---- gemm1 (MFMA): h0' = (x@W1)*dinv; dinv hoisted pre-K-loop --------------
// 64 rows x 128 cols/block; 4 waves 2x2; wave 32x64 = 2x4 frags.
__global__ __launch_bounds__(256, 2) void k_gemm1p(
    const void* __restrict__ x, const unsigned* __restrict__ det,
    const unsigned short* __restrict__ bth,
    const unsigned short* __restrict__ btl,
    const float* __restrict__ dinv,
    unsigned* __restrict__ Cp, int N) {
    const int lane = threadIdx.x & 63;
    const int wid  = threadIdx.x >> 6;
    const int wr = wid >> 1, wc = wid & 1;
    const int l15 = lane & 15, lg = lane >> 4;
    const long long r0 = (long long)blockIdx.x * 64 + wr * 32;
    long long ar[2];
#pragma unroll
    for (int m = 0; m < 2; ++m) {
        long long r = r0 + m * 16 + l15;
        ar[m] = (r < N) ? r : (N - 1);
    }
    int bn[4];
#pragma unroll
    for (int n = 0; n < 4; ++n) bn[n] = wc * 64 + n * 16 + l15;

    // hoist dinv for this thread's 8 output rows (independent of K-loop)
    float dv[2][4];
#pragma unroll
    for (int m = 0; m < 2; ++m)
#pragma unroll
        for (int r = 0; r < 4; ++r) {
            long long row = r0 + m * 16 + lg * 4 + r;
            dv[m][r] = dinv[(row < N) ? row : (N - 1)];
        }

    f32x4 acc[2][4] = {};
    if (!det[0]) {                                // x is bf16
        const unsigned short* xp = (const unsigned short*)x;
#pragma unroll
        for (int k0 = 0; k0 < 256; k0 += 32) {
            const int kb = k0 + lg * 8;
            s16x8 a[2], bh[4], bl[4];
#pragma unroll
            for (int m = 0; m < 2; ++m) a[m] = ld8u(xp + ar[m] * 256 + kb);
#pragma unroll
            for (int n = 0; n < 4; ++n) {
                bh[n] = ld8u(bth + (long long)bn[n] * 256 + kb);
                bl[n] = ld8u(btl + (long long)bn[n] * 256 + kb);
            }
#pragma unroll
            for (int m = 0; m < 2; ++m)
#pragma unroll
                for (int n = 0; n < 4; ++n) {
                    acc[m][n] = mfma16(a[m], bh[n], acc[m][n]);
                    acc[m][n] = mfma16(a[m], bl[n], acc[m][n]);
                }
        }
    } else {                                      // x is fp32: split hi/lo too
        const float* xp = (const float*)x;
#pragma unroll 2
        for (int k0 = 0; k0 < 256; k0 += 32) {
            const int kb = k0 + lg * 8;
            s16x8 ah[2], al[2], bh[4], bl[4];
#pragma unroll
            for (int m = 0; m < 2; ++m) cvt_hl(xp + ar[m] * 256 + kb, ah[m], al[m]);
#pragma unroll
            for (int n = 0; n < 4; ++n) {
                bh[n] = ld8u(bth + (long long)bn[n] * 256 + kb);
                bl[n] = ld8u(btl + (long long)bn[n] * 256 + kb);
            }
#pragma unroll
            for (int m = 0; m < 2; ++m)
#pragma unroll
                for (int n = 0; n < 4; ++n) {
                    acc[m][n] = mfma16(ah[m], bh[n], acc[m][n]);
                    acc[m][n] = mfma16(ah[m], bl[n], acc[m][n]);
                    acc[m][n] = mfma16(al[m], bh[n], acc[m][n]);
                }
        }
    }
    // epilogue: pure scale+pack+store (dinv already in regs)
#pragma unroll
    for (int m = 0; m < 2; ++m)
#pragma unroll
        for (int n = 0; n < 4; ++n) {
            const int col = wc * 64 + n * 16 + l15;
#pragma unroll
            for (int r = 0; r < 4; ++r) {
                long long row = r0 + m * 16 + lg * 4 + r;
                float v = acc[m][n][r] * dv[m][r];
                float p = __shfl_xor(v, 1);
                if (!(lane & 1) && row < N)
                    Cp[row * 64 + (col >> 1)] = pack2(v, p);
            }
        }
}

// ---- gemm2 (MFMA): [mu|lv] = ha @ [Wmu;Wlv] + bias; bias hoisted -----------
// In-place over ha panel: __syncthreads() between K-loop and epilogue.
__global__ __launch_bounds__(256, 2) void k_gemm2p(
    const unsigned short* __restrict__ hap,
    const unsigned short* __restrict__ bth,
    const unsigned short* __restrict__ btl,
    const void* bmu, const void* blv, const unsigned* __restrict__ det,
    float* __restrict__ outMu, float* __restrict__ outLv, int N) {
    const int lane = threadIdx.x & 63;
    const int wid  = threadIdx.x >> 6;
    const int wr = wid >> 1, wc = wid & 1;
    const int l15 = lane & 15, lg = lane >> 4;
    const long long r0 = (long long)blockIdx.x * 64 + wr * 32;
    long long ar[2];
#pragma unroll
    for (int m = 0; m < 2; ++m) {
        long long r = r0 + m * 16 + l15;
        ar[m] = (r < N) ? r : (N - 1);
    }
    int bn[4];
#pragma unroll
    for (int n = 0; n < 4; ++n) bn[n] = wc * 64 + n * 16 + l15;

    // hoist bias for this thread's 4 output cols (independent of K-loop)
    const unsigned wf = det[1];
    float bs[4];
#pragma unroll
    for (int n = 0; n < 4; ++n) {
        const int col = wc * 64 + n * 16 + l15;
        bs[n] = (col < 64) ? ldf(bmu, col, wf) : ldf(blv, col - 64, wf);
    }

    f32x4 acc[2][4] = {};
#pragma unroll
    for (int k0 = 0; k0 < 128; k0 += 32) {
        const int kb = k0 + lg * 8;
        s16x8 a[2], bh[4], bl[4];
#pragma unroll
        for (int m = 0; m < 2; ++m) a[m] = ld8u(hap + ar[m] * 128 + kb);
#pragma unroll
        for (int n = 0; n < 4; ++n) {
            bh[n] = ld8u(bth + (long long)bn[n] * 128 + kb);
            bl[n] = ld8u(btl + (long long)bn[n] * 128 + kb);
        }
#pragma unroll
        for (int m = 0; m < 2; ++m)
#pragma unroll
            for (int n = 0; n < 4; ++n) {
                acc[m][n] = mfma16(a[m], bh[n], acc[m][n]);
                acc[m][n] = mfma16(a[m], bl[n], acc[m][n]);
            }
    }
    __syncthreads();   // all A-reads done before any in-place mu write
#pragma unroll
    for (int m = 0; m < 2; ++m)
#pragma unroll
        for (int n = 0; n < 4; ++n) {
            const int col = wc * 64 + n * 16 + l15;
#pragma unroll
            for (int r = 0; r < 4; ++r) {
                long long row = r0 + m * 16 + lg * 4 + r;
                if (row < N) {
                    float v = acc[m][n][r] + bs[n];
                    if (col < 64) outMu[row * 64 + col] = v;
                    else          outLv[row * 64 + (col - 64)] = v;
                }
            }
        }
}

// ---- gather over pre-scaled bf16[N,128] panel ------------------------------
// out[node] = op( dinv[node] * (sum_{s in nbrs} h'[s] + h'[node]) )
// 4 nodes/wave: 16 lanes/node x uint4 (8 cols/lane), 8-way unroll -> 32 rows
// in flight per wave. pos = exclusive start (not mutated).
__global__ __launch_bounds__(256) void k_gather(const uint4* __restrict__ hp4,
                                                const int* __restrict__ srt,
                                                const int* __restrict__ cnt,
                                                const int* __restrict__ pos,
                                                const float* __restrict__ dinv,
                                                const void* bias, const unsigned* det,
                                                int leaky, int prescaleOut,
                                                uint4* __restrict__ outp4, int N) {
    int node = blockIdx.x * 16 + (threadIdx.x >> 4);
    if (node >= N) return;
    int lane4 = threadIdx.x & 15;
    int beg = pos[node];
    int end = beg + cnt[node];
    float dd = dinv[node];
    uint4 hv = hp4[(long long)node * 16 + lane4];
    float a[8];
    a[0] = bf2f((unsigned short)(hv.x & 0xffffu));
    a[1] = bf2f((unsigned short)(hv.x >> 16));
    a[2] = bf2f((unsigned short)(hv.y & 0xffffu));
    a[3] = bf2f((unsigned short)(hv.y >> 16));
    a[4] = bf2f((unsigned short)(hv.z & 0xffffu));
    a[5] = bf2f((unsigned short)(hv.z >> 16));
    a[6] = bf2f((unsigned short)(hv.w & 0xffffu));
    a[7] = bf2f((unsigned short)(hv.w >> 16));
    for (int q = beg; q < end; q += 8) {
        int s[8];
        uint4 v[8];
#pragma unroll
        for (int j = 0; j < 8; ++j) {
            int qq = q + j;
            s[j] = srt[(qq < end) ? qq : beg];   // loop entered => beg valid
        }
#pragma unroll
        for (int j = 0; j < 8; ++j)
            v[j] = hp4[(long long)s[j] * 16 + lane4];
#pragma unroll
        for (int j = 0; j < 8; ++j) {
            bool on = (q + j) < end;
            a[0] += on ? bf2f((unsigned short)(v[j].x & 0xffffu)) : 0.f;
            a[1] += on ? bf2f((unsigned short)(v[j].x >> 16)) : 0.f;
            a[2] += on ? bf2f((unsigned short)(v[j].y & 0xffffu)) : 0.f;
            a[3] += on ? bf2f((unsigned short)(v[j].y >> 16)) : 0.f;
            a[4] += on ? bf2f((unsigned short)(v[j].z & 0xffffu)) : 0.f;
            a[5] += on ? bf2f((unsigned short)(v[j].z >> 16)) : 0.f;
            a[6] += on ? bf2f((unsigned short)(v[j].w & 0xffffu)) : 0.f;
            a[7] += on ? bf2f((unsigned short)(v[j].w >> 16)) : 0.f;
        }
    }
#pragma unroll
    for (int t = 0; t < 8; ++t) a[t] *= dd;
    if (bias) {
#pragma unroll
        for (int t = 0; t < 8; ++t) a[t] += ldf(bias, 8 * lane4 + t, det[1]);
    }
    if (leaky) {
#pragma unroll
        for (int t = 0; t < 8; ++t) a[t] = (a[t] >= 0.f) ? a[t] : 0.01f * a[t];
    }
    if (prescaleOut) {
#pragma unroll
        for (int t = 0; t < 8; ++t) a[t] *= dd;
    }
    uint4 o;
    o.x = pack2(a[0], a[1]);
    o.y = pack2(a[2], a[3]);
    o.z = pack2(a[4], a[5]);
    o.w = pack2(a[6], a[7]);
    outp4[(long long)node * 16 + lane4] = o;
}

__global__ void k_sentinel(float* out, long long lvOff) {
    if (threadIdx.x == 0 && blockIdx.x == 0) {
        out[0] = 9.99e5f;
        out[lvOff] = 9.98e5f;
    }
}

extern "C" void kernel_launch(void* const* d_in, const int* in_sizes, int n_in,
                              void* d_out, int out_size, void* d_ws, size_t ws_size,
                              hipStream_t stream) {
    (void)out_size;
    const int N = 100000, E = 1600000;
    bool ok = (n_in == 8) && in_sizes[0] == 25600000 && in_sizes[1] == 3200000 &&
              in_sizes[2] == 32768 && in_sizes[3] == 128 &&
              in_sizes[4] == 8192 && in_sizes[5] == 64 &&
              in_sizes[6] == 8192 && in_sizes[7] == 64 &&
              ws_size >= (size_t)21 * 1024 * 1024;
    if (!ok) {
        k_sentinel<<<1, 64, 0, stream>>>((float*)d_out, (long long)N * 64);
        return;
    }
    const void* x   = d_in[0];
    const void* ei  = d_in[1];
    const void* W1  = d_in[2];
    const void* b1  = d_in[3];
    const void* Wmu = d_in[4];
    const void* bmu = d_in[5];
    const void* Wlv = d_in[6];
    const void* blv = d_in[7];

    char* w = (char*)d_ws;
    auto carve = [&](size_t bytes) {
        char* p = w;
        w += (bytes + 255) & ~(size_t)255;
        return p;
    };
    unsigned* flags = (unsigned*)carve(64);
    int*    cnt  = (int*)carve((size_t)N * 4);
    int*    pos  = (int*)carve((size_t)N * 4);
    float*  dinv = (float*)carve((size_t)N * 4);
    int*    bsum = (int*)carve(4096);
    int*    srt  = (int*)carve((size_t)E * 4);
    unsigned short* bt1h = (unsigned short*)carve(128 * 256 * 2);  // 64KB
    unsigned short* bt1l = (unsigned short*)carve(128 * 256 * 2);
    unsigned short* bt2h = (unsigned short*)carve(128 * 128 * 2);  // 32KB
    unsigned short* bt2l = (unsigned short*)carve(128 * 128 * 2);
    int*      btail  = (int*)carve((size_t)NBKT * 8 * 4);               // 25KB
    unsigned* bstore = (unsigned*)carve((size_t)NBKT * 8 * CAPS * 4);   // 12.8MB
    // total ~20.6MB

    float* M = (float*)d_out;                  // mu region / panel storage
    float* L = M + (size_t)N * 64;             // logvar region / panel storage
    unsigned* Mp = (unsigned*)M;               // bf16[N,128] as dword[N*64]
    unsigned* Lp = (unsigned*)L;

    const int nb = (N + 1023) / 1024;
    const int ggrid = N / 16;                  // 6250 (N % 16 == 0)
    const int gb64 = (N + 63) / 64;            // 1563

    k_detect<<<1, 256, 0, stream>>>(x, W1, ei, flags, btail);
    k_wsplit<<<(256 * 128 + 128 * 128 + 255) / 256, 256, 0, stream>>>(
        W1, Wmu, Wlv, flags, bt1h, bt1l, bt2h, bt2l);

    // bucketed counting sort
    k_bucket<<<(E + 255) / 256, 256, 0, stream>>>(ei, flags, btail, bstore, E, N);
    k_bhist<<<NBKT, 256, 0, stream>>>(btail, bstore, cnt, dinv, N);
    k_scan_blk<<<nb, 256, 0, stream>>>(cnt, pos, bsum, N);
    k_scan_add<<<nb, 256, 0, stream>>>(pos, bsum, N);
    k_emit<<<NBKT, 256, 0, stream>>>(btail, bstore, pos, srt, N);

    // h0' = (x@W1) * dinv[row]  -> bf16 panel in M   (MFMA)
    k_gemm1p<<<gb64, 256, 0, stream>>>(x, flags, bt1h, bt1l, dinv, Mp, N);
    // h'  = leaky(dd*(sum+self) + b1) * dd -> bf16 panel in L
    k_gather<<<ggrid, 256, 0, stream>>>((const uint4*)Mp, srt, cnt, pos, dinv,
                                        b1, flags, 1, 1, (uint4*)Lp, N);
    // ha  = dd*(sum+self) -> bf16 panel in M (h0' dead)
    k_gather<<<ggrid, 256, 0, stream>>>((const uint4*)Lp, srt, cnt, pos, dinv,
                                        nullptr, flags, 0, 0, (uint4*)Mp, N);
    // [mu|lv] = ha @ [Wmu;Wlv] + bias -> fp32 M/L in-place  (MFMA)
    k_gemm2p<<<gb64, 256, 0, stream>>>((const unsigned short*)Mp, bt2h, bt2l,
                                       bmu, blv, flags, M, L, N);
}